// Round 3
// baseline (632.358 us; speedup 1.0000x reference)
//
#include <hip/hip_runtime.h>

// Problem constants
#define C_DIM 512
#define V_DIM 1024

typedef __attribute__((ext_vector_type(8))) short short8;    // 8 bf16 (4 VGPRs)
typedef __attribute__((ext_vector_type(4))) float f32x4;
typedef __attribute__((ext_vector_type(16))) float f32x16;   // 32x32 MFMA acc

__device__ __forceinline__ short f2bf(float f) {
  unsigned int u = __float_as_uint(f);
  u += 0x7fffu + ((u >> 16) & 1u);           // RNE
  return (short)(u >> 16);
}

__device__ __forceinline__ float fast_tanh_f(float x) {
  // tanh(x) = 1 - 2/(exp(2x)+1); saturates correctly at +/-inf
  float e = __expf(2.0f * x);
  return fmaf(-2.0f, __builtin_amdgcn_rcpf(e + 1.0f), 1.0f);
}

// ---------------------------------------------------------------------------
// Kernel 1 (unchanged, harness-verified): cast W (V,C) fp32 -> bf16 into the
// 32x32-MFMA B-fragment image:
//   chunk (vt,kc) = 16 KB; inside: [wn(4)][nt(2)][s(2)][hi(2)][c32(32)] x 16B
//   element (v,c): v = vt*256 + wn*64 + nt*32 + c32
//                  c = kc*32 + s*16 + hi*8 + j   (j = 0..7 inside the 16B)
// ---------------------------------------------------------------------------
__global__ __launch_bounds__(256) void wswz_kernel(const float* __restrict__ W,
                                                   char* __restrict__ wsw) {
  const int i = blockIdx.x * 256 + threadIdx.x;   // 65536 threads
  const int v = i >> 6;
  const int c0 = (i & 63) << 3;
  const float* wp = W + (size_t)v * C_DIM + c0;
  const f32x4 w0 = *(const f32x4*)(wp);
  const f32x4 w1 = *(const f32x4*)(wp + 4);
  short8 pk;
  pk[0] = f2bf(w0[0]); pk[1] = f2bf(w0[1]); pk[2] = f2bf(w0[2]); pk[3] = f2bf(w0[3]);
  pk[4] = f2bf(w1[0]); pk[5] = f2bf(w1[1]); pk[6] = f2bf(w1[2]); pk[7] = f2bf(w1[3]);
  const int vt = v >> 8, vloc = v & 255;
  const int wn = vloc >> 6, nt = (vloc >> 5) & 1, c32 = vloc & 31;
  const int kc = c0 >> 5, s = (c0 >> 4) & 1, hi = (c0 >> 3) & 1;
  char* dst = wsw + (size_t)(vt * 16 + kc) * 16384 +
              wn * 4096 + nt * 2048 + s * 1024 + hi * 512 + c32 * 16;
  *(short8*)dst = pk;
}

// ---------------------------------------------------------------------------
// Kernel 2: persistent-A joiner, SLIM register variant.
//   Same proven skeleton as before (2048 blocks, 4 waves, 64-row panels,
//   barrier-free main loop, 64 KB LDS, 2 blocks/CU) with:
//     - A ping-pong REMOVED: A image is static after phase 1, so fragments
//       are ds_read just-in-time (s0 frags first -> MFMA starts at lgkm(2)).
//       Frees 32 VGPRs and 4 in-flight lgkm ops per iteration.
//     - B ping-pong kept (global->reg from L2-resident wsw, 1 chunk ahead).
//     - vt loop pinned to unroll 1 (code size / pressure control).
//   Target: ~140 VGPRs, zero spill.
// ---------------------------------------------------------------------------
__global__ __launch_bounds__(256, 2) void joiner_kernel(
    const float* __restrict__ enc, const float* __restrict__ pred,
    const char* __restrict__ wsw, const float* __restrict__ bias,
    float* __restrict__ out) {
  extern __shared__ char smem[];          // 65536 B A image
  const int tid = threadIdx.x;
  const int lane = tid & 63;
  const int wn = tid >> 6;                // wave 0..3 = 64-col block
  const int l31 = lane & 31, hf = lane >> 5;

  // Bijective XCD swizzle (2048 % 8 == 0): 256 consecutive panels per XCD.
  const int bid = blockIdx.x;
  const int rp = ((bid & 7) << 8) | (bid >> 3);   // row panel 0..2047
  const int n = rp >> 8;                  // batch (rp = n*256 + t)

  // ---- Phase 1: stage A = tanh(enc+pred), 64 rows x 512 k, bf16 (64 KB)
  // Image: [kc(16)][mt(2)][s(2)][hi(2)][r32(32)] x 16 B; one barrier total.
  {
    const int u = ((tid >> 7) << 5) + (tid & 31);
    const int koff = ((tid >> 6) & 1) * 16 + ((tid >> 5) & 1) * 8;
    const float* pe = enc + (size_t)rp * C_DIM + koff;
    const float* pp = pred + ((size_t)(n * 64 + u)) * C_DIM + koff;
    char* adst = smem + tid * 16;                 // linear ds_write_b128
#pragma unroll 4
    for (int kc = 0; kc < 16; ++kc) {
      const f32x4 e0 = *(const f32x4*)(pe + kc * 32);
      const f32x4 e1 = *(const f32x4*)(pe + kc * 32 + 4);
      const f32x4 p0 = *(const f32x4*)(pp + kc * 32);
      const f32x4 p1 = *(const f32x4*)(pp + kc * 32 + 4);
      short8 pk;
      pk[0] = f2bf(fast_tanh_f(e0[0] + p0[0]));
      pk[1] = f2bf(fast_tanh_f(e0[1] + p0[1]));
      pk[2] = f2bf(fast_tanh_f(e0[2] + p0[2]));
      pk[3] = f2bf(fast_tanh_f(e0[3] + p0[3]));
      pk[4] = f2bf(fast_tanh_f(e1[0] + p1[0]));
      pk[5] = f2bf(fast_tanh_f(e1[1] + p1[1]));
      pk[6] = f2bf(fast_tanh_f(e1[2] + p1[2]));
      pk[7] = f2bf(fast_tanh_f(e1[3] + p1[3]));
      *(short8*)(adst + kc * 4096) = pk;
    }
  }
  __syncthreads();                        // the ONLY barrier

  // ---- fragment bases
  // A frag (kc, f=mt*2+s): smem + kc*4096 + f*1024 + hf*512 + l31*16
  const char* ab = smem + hf * 512 + l31 * 16;
  // B frag (g, f=nt*2+s): wsw + g*16384 + wn*4096 + f*1024 + hf*512 + l31*16
  const char* wb = wsw + wn * 4096 + hf * 512 + l31 * 16;

  f32x16 acc[2][2];
#pragma unroll
  for (int mt = 0; mt < 2; ++mt)
#pragma unroll
    for (int nt = 0; nt < 2; ++nt)
#pragma unroll
      for (int r = 0; r < 16; ++r) acc[mt][nt][r] = 0.0f;

  short8 bfr[2][4];                       // B ping-pong only

  // ---- prologue: B fragments for g = 0 (vt=0, kc=0)
#pragma unroll
  for (int f = 0; f < 4; ++f) bfr[0][f] = *(const short8*)(wb + f * 1024);

#pragma unroll 1
  for (int vt = 0; vt < 4; ++vt) {
    const char* wg = wb + (size_t)vt * 262144;    // this v-tile's 16 chunks
#pragma unroll
    for (int kc = 0; kc < 16; ++kc) {
      const int cb = kc & 1, nb = cb ^ 1;         // static after full unroll

      // B prefetch for g+1, issued first (longest time in flight)
      if (kc < 15 || vt < 3) {
        const char* bp = wg + (kc + 1) * 16384;
#pragma unroll
        for (int f = 0; f < 4; ++f)
          bfr[nb][f] = *(const short8*)(bp + f * 1024);
      }

      // A fragments just-in-time; s0 frags first so MFMA starts at lgkm(2)
      const char* ap = ab + kc * 4096;
      const short8 a_m0s0 = *(const short8*)(ap);           // f0
      const short8 a_m1s0 = *(const short8*)(ap + 2048);    // f2
      const short8 a_m0s1 = *(const short8*)(ap + 1024);    // f1
      const short8 a_m1s1 = *(const short8*)(ap + 3072);    // f3

      __builtin_amdgcn_s_setprio(1);
      acc[0][0] = __builtin_amdgcn_mfma_f32_32x32x16_bf16(a_m0s0, bfr[cb][0], acc[0][0], 0, 0, 0);
      acc[0][1] = __builtin_amdgcn_mfma_f32_32x32x16_bf16(a_m0s0, bfr[cb][2], acc[0][1], 0, 0, 0);
      acc[1][0] = __builtin_amdgcn_mfma_f32_32x32x16_bf16(a_m1s0, bfr[cb][0], acc[1][0], 0, 0, 0);
      acc[1][1] = __builtin_amdgcn_mfma_f32_32x32x16_bf16(a_m1s0, bfr[cb][2], acc[1][1], 0, 0, 0);
      acc[0][0] = __builtin_amdgcn_mfma_f32_32x32x16_bf16(a_m0s1, bfr[cb][1], acc[0][0], 0, 0, 0);
      acc[0][1] = __builtin_amdgcn_mfma_f32_32x32x16_bf16(a_m0s1, bfr[cb][3], acc[0][1], 0, 0, 0);
      acc[1][0] = __builtin_amdgcn_mfma_f32_32x32x16_bf16(a_m1s1, bfr[cb][1], acc[1][0], 0, 0, 0);
      acc[1][1] = __builtin_amdgcn_mfma_f32_32x32x16_bf16(a_m1s1, bfr[cb][3], acc[1][1], 0, 0, 0);
      __builtin_amdgcn_s_setprio(0);
    }

    // ---- epilogue for this v-tile (no barrier; overlaps resident waves)
    // C/D layout (m74/m101): col = lane&31, row = (r&3) + 8*(r>>2) + 4*hf
    {
      const int colb = (vt << 8) + (wn << 6) + l31;
      float* ob = out + ((size_t)rp * 64 + hf * 4) * V_DIM + colb;
#pragma unroll
      for (int nt = 0; nt < 2; ++nt) {
        const float bb = bias[colb + nt * 32];
#pragma unroll
        for (int mt = 0; mt < 2; ++mt) {
#pragma unroll
          for (int r = 0; r < 16; ++r) {
            const int row_off = mt * 32 + (r & 3) + 8 * (r >> 2);
            __builtin_nontemporal_store(acc[mt][nt][r] + bb,
                                        ob + (size_t)row_off * V_DIM + nt * 32);
            acc[mt][nt][r] = 0.0f;        // reset for next v-tile
          }
        }
      }
    }
  }
}

extern "C" void kernel_launch(void* const* d_in, const int* in_sizes, int n_in,
                              void* d_out, int out_size, void* d_ws, size_t ws_size,
                              hipStream_t stream) {
  const float* enc  = (const float*)d_in[0];   // (8,256,512)
  const float* pred = (const float*)d_in[1];   // (8,64,512)
  const float* W    = (const float*)d_in[2];   // (1024,512)
  const float* bias = (const float*)d_in[3];   // (1024,)
  float* out = (float*)d_out;                  // (8,256,64,1024)
  char* wsw = (char*)d_ws;                     // 1 MB swizzled bf16 W

  wswz_kernel<<<dim3(256), dim3(256), 0, stream>>>(W, wsw);

  (void)hipFuncSetAttribute((const void*)joiner_kernel,
                            hipFuncAttributeMaxDynamicSharedMemorySize, 65536);
  joiner_kernel<<<dim3(2048), dim3(256), 65536, stream>>>(enc, pred, wsw, bias, out);
}